// Round 5
// baseline (417.857 us; speedup 1.0000x reference)
//
#include <hip/hip_runtime.h>
#include <hip/hip_cooperative_groups.h>

namespace cg = cooperative_groups;

#define CC 128
#define NUNITS 1024

// Bilinear sample from a zero-border padded LDS plane.
// pl is [H+3][stride] with interior pixel (r,c) at pl[(r+1)*stride + (c+1)],
// border rows/cols are 0. Coords clamped to [-1, W]; out-of-range taps read 0.
__device__ __forceinline__ float sample_pad(const float* pl, int stride,
                                            float WF, float ix, float iy) {
  ix = fminf(fmaxf(ix, -1.0f), WF);
  iy = fminf(fmaxf(iy, -1.0f), WF);
  float x0f = floorf(ix), y0f = floorf(iy);
  float wx = ix - x0f, wy = iy - y0f;
  int xi = (int)x0f + 1, yi = (int)y0f + 1;
  const float* p0 = pl + yi * stride + xi;
  float v00 = p0[0], v01 = p0[1], v10 = p0[stride], v11 = p0[stride + 1];
  return (1.0f - wy) * ((1.0f - wx) * v00 + wx * v01) +
         wy * ((1.0f - wx) * v10 + wx * v11);
}

// Factorized box mask: validity of tap(i,j) = X_i * Y_j, so bilinear sum = mx*my.
__device__ __forceinline__ float box_mask(float bix, float biy, float WM1) {
  float bx0 = floorf(bix), by0 = floorf(biy);
  float bwx = bix - bx0, bwy = biy - by0;
  float mx = (((bx0 >= 0.0f) && (bx0 <= WM1)) ? (1.0f - bwx) : 0.0f) +
             (((bx0 >= -1.0f) && (bx0 <= WM1 - 1.0f)) ? bwx : 0.0f);
  float my = (((by0 >= 0.0f) && (by0 <= WM1)) ? (1.0f - bwy) : 0.0f) +
             (((by0 >= -1.0f) && (by0 <= WM1 - 1.0f)) ? bwy : 0.0f);
  return mx * my;
}

// ==================== stage bodies (shared by coop + fallback paths) ===============

// S0: inLay combine(Ci=3) + sample + box mask; unit u = b*128+c. cp: 67*68 floats.
__device__ void stage_inlay(int u, int tid, float* cp, const float* x,
                            const float* lin0, const float* geo0, const float* box0,
                            const float* db, float* ws1, float* head) {
  const int W = 64, HW = 4096;
  int b = u >> 7, c = u & (CC - 1);
  if (u == 0 && tid < 80) head[tid] = db[tid % 10];  // bias init for atomic dense
  const float* xb = x + (size_t)b * 3 * HW;
  float w0 = lin0[c * 3 + 0], w1 = lin0[c * 3 + 1], w2 = lin0[c * 3 + 2];
  if (tid < 68) {
    cp[tid] = 0.0f; cp[65 * 68 + tid] = 0.0f; cp[66 * 68 + tid] = 0.0f;
  } else if (tid < 132) {
    int r = tid - 67;
    cp[r * 68 + 0] = 0.0f; cp[r * 68 + 65] = 0.0f; cp[r * 68 + 66] = 0.0f;
  }
#pragma unroll
  for (int k = 0; k < 4; ++k) {
    int i4 = tid + k * 256;
    int base = i4 * 4;
    float4 f0 = *reinterpret_cast<const float4*>(&xb[base]);
    float4 f1 = *reinterpret_cast<const float4*>(&xb[HW + base]);
    float4 f2 = *reinterpret_cast<const float4*>(&xb[2 * HW + base]);
    int h = i4 >> 4, w = (i4 & 15) * 4;
    float* d = &cp[(h + 1) * 68 + w + 1];
    d[0] = w0 * f0.x + w1 * f1.x + w2 * f2.x;
    d[1] = w0 * f0.y + w1 * f1.y + w2 * f2.y;
    d[2] = w0 * f0.z + w1 * f1.z + w2 * f2.z;
    d[3] = w0 * f0.w + w1 * f1.w + w2 * f2.w;
  }
  __syncthreads();
  const float* g = geo0 + c * 6;
  const float* bp = box0 + c * 6;
  float g0 = g[0], g1 = g[1], g2 = g[2], g3 = g[3], g4 = g[4], g5 = g[5];
  float b0 = bp[0], b1 = bp[1], b2 = bp[2], b3 = bp[3], b4 = bp[4], b5 = bp[5];
  float* o = ws1 + (size_t)u * HW;
#pragma unroll
  for (int k = 0; k < 16; ++k) {
    int px = tid + k * 256;
    int h = px >> 6, w = px & 63;
    float xs = (2.0f * w + 1.0f) / W - 1.0f;
    float ys = (2.0f * h + 1.0f) / W - 1.0f;
    float ix = ((g0 * xs + g1 * ys + g2 + 1.0f) * W - 1.0f) * 0.5f;
    float iy = ((g3 * xs + g4 * ys + g5 + 1.0f) * W - 1.0f) * 0.5f;
    float samp = sample_pad(cp, 68, 64.0f, ix, iy);
    float bix = ((b0 * xs + b1 * ys + b2 + 1.0f) * W - 1.0f) * 0.5f;
    float biy = ((b3 * xs + b4 * ys + b5 + 1.0f) * W - 1.0f) * 0.5f;
    o[px] = samp * box_mask(bix, biy, 63.0f);
  }
}

// S1: layer-0 GEMM 64x64 tile. unit u: b = u>>7, t = u&127 -> row0=(t&1)*64, col0=(t>>1)*64.
// As: 16*68 floats, Bs: 16*64 floats.
__device__ void stage_gemm64(int u, int tid, float* As, float* Bs,
                             const float* lw, const float* xin, float* yout) {
  const int Ci = 128, HW = 4096;
  int b = u >> 7, t = u & 127;
  int row0 = (t & 1) * 64;
  int col0 = (t >> 1) * 64;
  const float* xb = xin + (size_t)b * Ci * HW;
  float* yb = yout + (size_t)b * CC * HW;
  int tx = tid & 15, ty = tid >> 4;
  int m = tid >> 2, kq = (tid & 3) * 4;
  int kk = tid >> 4, n4 = (tid & 15) * 4;
  float acc[4][4] = {};
  float4 ra = *reinterpret_cast<const float4*>(&lw[(row0 + m) * Ci + kq]);
  float4 rb = *reinterpret_cast<const float4*>(&xb[(size_t)kk * HW + col0 + n4]);
  for (int k0 = 0; k0 < 128; k0 += 16) {
    __syncthreads();
    As[(kq + 0) * 68 + m] = ra.x; As[(kq + 1) * 68 + m] = ra.y;
    As[(kq + 2) * 68 + m] = ra.z; As[(kq + 3) * 68 + m] = ra.w;
    *reinterpret_cast<float4*>(&Bs[kk * 64 + n4]) = rb;
    __syncthreads();
    if (k0 + 16 < 128) {
      ra = *reinterpret_cast<const float4*>(&lw[(row0 + m) * Ci + k0 + 16 + kq]);
      rb = *reinterpret_cast<const float4*>(&xb[(size_t)(k0 + 16 + kk) * HW + col0 + n4]);
    }
#pragma unroll
    for (int kki = 0; kki < 16; ++kki) {
      float4 a4 = *reinterpret_cast<const float4*>(&As[kki * 68 + ty * 4]);
      float4 b4 = *reinterpret_cast<const float4*>(&Bs[kki * 64 + tx * 4]);
      float a[4] = {a4.x, a4.y, a4.z, a4.w};
      float bv[4] = {b4.x, b4.y, b4.z, b4.w};
#pragma unroll
      for (int i = 0; i < 4; i++)
#pragma unroll
        for (int j = 0; j < 4; j++) acc[i][j] += a[i] * bv[j];
    }
  }
#pragma unroll
  for (int i = 0; i < 4; i++) {
    float* yr = yb + (size_t)(row0 + ty * 4 + i) * HW + col0 + tx * 4;
    *reinterpret_cast<float4*>(yr) = make_float4(acc[i][0], acc[i][1], acc[i][2], acc[i][3]);
  }
}

// S2: sample 64x64 + MaxPool2d_G -> 32x32. sp: 64*68, pl(==cb): 67*68 floats.
__device__ void stage_sampmax(int u, int tid, float* sp, float* pl,
                              float* wv, int* wi, int* am_s,
                              const float* yin, const float* geo, const float* box,
                              float* outp) {
  float* cb = pl;
  int c = u & (CC - 1);
  if (tid < 68) {
    pl[tid] = 0.0f; pl[65 * 68 + tid] = 0.0f; pl[66 * 68 + tid] = 0.0f;
  } else if (tid < 132) {
    int r = tid - 67;
    pl[r * 68 + 0] = 0.0f; pl[r * 68 + 65] = 0.0f; pl[r * 68 + 66] = 0.0f;
  }
  {
    const float* plane = yin + (size_t)u * 4096;
#pragma unroll
    for (int k = 0; k < 4; ++k) {
      int i4 = tid + k * 256;
      float4 f = *reinterpret_cast<const float4*>(&plane[i4 * 4]);
      int h = i4 >> 4, w = (i4 & 15) * 4;
      float* d = &pl[(h + 1) * 68 + w + 1];
      d[0] = f.x; d[1] = f.y; d[2] = f.z; d[3] = f.w;
    }
  }
  __syncthreads();
  {
    const float* g = geo + c * 6;
    const float* bp = box + c * 6;
    float g0 = g[0], g1 = g[1], g2 = g[2], g3 = g[3], g4 = g[4], g5 = g[5];
    float b0 = bp[0], b1 = bp[1], b2 = bp[2], b3 = bp[3], b4 = bp[4], b5 = bp[5];
#pragma unroll
    for (int k = 0; k < 16; ++k) {
      int px = tid + k * 256;
      int h = px >> 6, w = px & 63;
      float xs = (2.0f * w + 1.0f) / 64.0f - 1.0f;
      float ys = (2.0f * h + 1.0f) / 64.0f - 1.0f;
      float ix = ((g0 * xs + g1 * ys + g2 + 1.0f) * 64.0f - 1.0f) * 0.5f;
      float iy = ((g3 * xs + g4 * ys + g5 + 1.0f) * 64.0f - 1.0f) * 0.5f;
      float samp = sample_pad(pl, 68, 64.0f, ix, iy);
      float bix = ((b0 * xs + b1 * ys + b2 + 1.0f) * 64.0f - 1.0f) * 0.5f;
      float biy = ((b3 * xs + b4 * ys + b5 + 1.0f) * 64.0f - 1.0f) * 0.5f;
      sp[h * 68 + w] = samp * box_mask(bix, biy, 63.0f);
    }
  }
  __syncthreads();
  // Phase 2: vertical 32-row sliding box sums -> cb (overwrites pl region)
  {
    int strip = tid >> 4, w4 = (tid & 15) * 4;
    int h0 = strip * 4;
    float4 a = make_float4(0.f, 0.f, 0.f, 0.f);
    float4 keep0 = a, keep1 = a, keep2 = a;
#pragma unroll
    for (int j = 0; j < 32; ++j) {
      int r = h0 + j - 16;
      bool valid = (r >= 0) && (r < 64);
      int rc = valid ? r : 0;
      float4 f = *reinterpret_cast<const float4*>(&sp[rc * 68 + w4]);
      f.x = valid ? f.x : 0.0f; f.y = valid ? f.y : 0.0f;
      f.z = valid ? f.z : 0.0f; f.w = valid ? f.w : 0.0f;
      if (j == 0) keep0 = f;
      if (j == 1) keep1 = f;
      if (j == 2) keep2 = f;
      a.x += f.x; a.y += f.y; a.z += f.z; a.w += f.w;
    }
    *reinterpret_cast<float4*>(&cb[(h0 + 0) * 68 + w4]) = a;
#pragma unroll
    for (int j = 32; j < 35; ++j) {
      int r = h0 + j - 16;
      bool valid = (r < 64);
      int rc = valid ? r : 0;
      float4 f = *reinterpret_cast<const float4*>(&sp[rc * 68 + w4]);
      f.x = valid ? f.x : 0.0f; f.y = valid ? f.y : 0.0f;
      f.z = valid ? f.z : 0.0f; f.w = valid ? f.w : 0.0f;
      float4 kp = (j == 32) ? keep0 : ((j == 33) ? keep1 : keep2);
      a.x += f.x - kp.x; a.y += f.y - kp.y; a.z += f.z - kp.z; a.w += f.w - kp.w;
      *reinterpret_cast<float4*>(&cb[(h0 + j - 31) * 68 + w4]) = a;
    }
  }
  __syncthreads();
  // Phase 3: horizontal 32-col sliding box sums + argmax
  float best = -3.402823466e+38f;
  int bidx = 0x7fffffff;
#pragma unroll
  for (int hh = 0; hh < 4; ++hh) {
    int h = (tid >> 4) + hh * 16;
    int w4 = (tid & 15) * 4;
    float s0 = 0.f, k0 = 0.f, k1 = 0.f, k2 = 0.f;
#pragma unroll
    for (int q = 0; q < 8; ++q) {
      int u0 = w4 - 16 + 4 * q;
      bool ok = (u0 >= 0) && (u0 <= 60);
      int uc = ok ? u0 : 0;
      float4 f = *reinterpret_cast<const float4*>(&cb[h * 68 + uc]);
      f.x = ok ? f.x : 0.0f; f.y = ok ? f.y : 0.0f;
      f.z = ok ? f.z : 0.0f; f.w = ok ? f.w : 0.0f;
      if (q == 0) { k0 = f.x; k1 = f.y; k2 = f.z; }
      s0 += f.x; s0 += f.y; s0 += f.z; s0 += f.w;
    }
    float ftx = 0.f, fty = 0.f, ftz = 0.f;
    {
      int u0 = w4 + 16;
      bool ok = (u0 <= 60);
      int uc = ok ? u0 : 0;
      float4 f = *reinterpret_cast<const float4*>(&cb[h * 68 + uc]);
      ftx = ok ? f.x : 0.0f; fty = ok ? f.y : 0.0f; ftz = ok ? f.z : 0.0f;
    }
    float s1 = s0 - k0 + ftx;
    float s2 = s1 - k1 + fty;
    float s3 = s2 - k2 + ftz;
    float sv[4] = {s0, s1, s2, s3};
#pragma unroll
    for (int d = 0; d < 4; ++d) {
      int i = (h << 6) + w4 + d;
      if (sv[d] > best) { best = sv[d]; bidx = i; }
    }
  }
#pragma unroll
  for (int off = 32; off > 0; off >>= 1) {
    float v2 = __shfl_down(best, off);
    int i2 = __shfl_down(bidx, off);
    if (v2 > best || (v2 == best && i2 < bidx)) { best = v2; bidx = i2; }
  }
  if ((tid & 63) == 0) { wv[tid >> 6] = best; wi[tid >> 6] = bidx; }
  __syncthreads();
  if (tid == 0) {
    float bv = wv[0]; int bi = wi[0];
#pragma unroll
    for (int k = 1; k < 4; ++k)
      if (wv[k] > bv || (wv[k] == bv && wi[k] < bi)) { bv = wv[k]; bi = wi[k]; }
    *am_s = bi;
  }
  __syncthreads();
  int am = *am_s;
  int r = am >> 6, cx = am & 63;
  float* o = outp + (size_t)u * 1024;
#pragma unroll
  for (int k = 0; k < 4; ++k) {
    int idx = tid + k * 256;
    int oi = idx >> 5, oj = idx & 31;
    int rr = r + oi - 16, cj = cx + oj - 16;
    bool v = (rr >= 0) && (rr < 64) && (cj >= 0) && (cj < 64);
    int rrc = v ? rr : 0, cjc = v ? cj : 0;
    o[idx] = v ? sp[rrc * 68 + cjc] : 0.0f;
  }
}

// S3/S5: 32x32-layer GEMM, 32x32 tile per unit. As: 16*36, Bs: 16*32 floats.
__device__ void stage_gemm32(int u, int tid, float* As, float* Bs,
                             const float* lw, const float* xin, float* yout) {
  int b = u >> 7, t = u & 127;
  int row0 = (t >> 5) * 32, col0 = (t & 31) * 32;
  const float* xb = xin + (size_t)b * 128 * 1024;
  float* yb = yout + (size_t)b * 128 * 1024;
  int ty = tid >> 4, tx = tid & 15;
  int am_ = tid >> 2, akq = (tid & 3) * 4;
  int bl = tid - 128, bkk = bl >> 3, bn4 = (bl & 7) * 4;
  float acc00 = 0.f, acc01 = 0.f, acc10 = 0.f, acc11 = 0.f;
  for (int k0 = 0; k0 < 128; k0 += 16) {
    __syncthreads();
    if (tid < 128) {
      float4 ra = *reinterpret_cast<const float4*>(&lw[(row0 + am_) * 128 + k0 + akq]);
      As[(akq + 0) * 36 + am_] = ra.x; As[(akq + 1) * 36 + am_] = ra.y;
      As[(akq + 2) * 36 + am_] = ra.z; As[(akq + 3) * 36 + am_] = ra.w;
    } else {
      float4 rb = *reinterpret_cast<const float4*>(&xb[(size_t)(k0 + bkk) * 1024 + col0 + bn4]);
      *reinterpret_cast<float4*>(&Bs[bkk * 32 + bn4]) = rb;
    }
    __syncthreads();
#pragma unroll
    for (int kki = 0; kki < 16; ++kki) {
      float2 av = *reinterpret_cast<const float2*>(&As[kki * 36 + ty * 2]);
      float2 bv = *reinterpret_cast<const float2*>(&Bs[kki * 32 + tx * 2]);
      acc00 += av.x * bv.x; acc01 += av.x * bv.y;
      acc10 += av.y * bv.x; acc11 += av.y * bv.y;
    }
  }
  *reinterpret_cast<float2*>(&yb[(size_t)(row0 + ty * 2) * 1024 + col0 + tx * 2]) =
      make_float2(acc00, acc01);
  *reinterpret_cast<float2*>(&yb[(size_t)(row0 + ty * 2 + 1) * 1024 + col0 + tx * 2]) =
      make_float2(acc10, acc11);
}

// S4/S6: 32x32 sample (+POOL: mean-pool + dense-head atomics). pl: 35*36, wred: 4.
template <bool POOL>
__device__ void stage_sample32(int u, int tid, float* pl, float* wred,
                               const float* yin, const float* geo, const float* box,
                               float* outp, const float* dw, float* head) {
  const int W = 32;
  int b = u >> 7, c = u & (CC - 1);
  if (tid < 36) {
    pl[tid] = 0.0f; pl[33 * 36 + tid] = 0.0f; pl[34 * 36 + tid] = 0.0f;
  } else if (tid < 68) {
    int r = tid - 35;
    pl[r * 36 + 0] = 0.0f; pl[r * 36 + 33] = 0.0f; pl[r * 36 + 34] = 0.0f; pl[r * 36 + 35] = 0.0f;
  }
  {
    const float* plane = yin + (size_t)u * 1024;
    float4 f = *reinterpret_cast<const float4*>(&plane[tid * 4]);
    int h = tid >> 3, w = (tid & 7) * 4;
    float* d = &pl[(h + 1) * 36 + w + 1];
    d[0] = f.x; d[1] = f.y; d[2] = f.z; d[3] = f.w;
  }
  __syncthreads();
  const float* g = geo + c * 6;
  const float* bp = box + c * 6;
  float g0 = g[0], g1 = g[1], g2 = g[2], g3 = g[3], g4 = g[4], g5 = g[5];
  float b0 = bp[0], b1 = bp[1], b2 = bp[2], b3 = bp[3], b4 = bp[4], b5 = bp[5];
  float* o = outp + (size_t)u * 1024;
  float psum = 0.f;
#pragma unroll
  for (int k = 0; k < 4; ++k) {
    int px = tid + k * 256;
    int h = px >> 5, w = px & 31;
    float xs = (2.0f * w + 1.0f) / W - 1.0f;
    float ys = (2.0f * h + 1.0f) / W - 1.0f;
    float ix = ((g0 * xs + g1 * ys + g2 + 1.0f) * W - 1.0f) * 0.5f;
    float iy = ((g3 * xs + g4 * ys + g5 + 1.0f) * W - 1.0f) * 0.5f;
    float samp = sample_pad(pl, 36, 32.0f, ix, iy);
    float bix = ((b0 * xs + b1 * ys + b2 + 1.0f) * W - 1.0f) * 0.5f;
    float biy = ((b3 * xs + b4 * ys + b5 + 1.0f) * W - 1.0f) * 0.5f;
    float res = samp * box_mask(bix, biy, 31.0f);
    o[px] = res;
    if (POOL) psum += res;
  }
  if (POOL) {
    int lane = tid & 63, wid = tid >> 6;
#pragma unroll
    for (int off = 32; off > 0; off >>= 1) psum += __shfl_down(psum, off);
    if (lane == 0) wred[wid] = psum;
    __syncthreads();
    if (tid < 10) {
      float tsum = (wred[0] + wred[1] + wred[2] + wred[3]) * (1.0f / 1024.0f);
      atomicAdd(&head[b * 10 + tid], tsum * dw[tid * 128 + c]);
    }
  }
}

// ======================= cooperative mega-kernel (grid-stride) =====================
__global__ __launch_bounds__(256, 4) void meganet_kernel(
    const float* x, const float* geo0, const float* lin0, const float* box0,
    const float* geos, const float* lins, const float* boxes, const float* dw,
    const float* db, float* out, float* ws0, float* ws1, float* ws2) {
  cg::grid_group grid = cg::this_grid();
  __shared__ __align__(16) float arena[8908];  // 35.6 KB
  __shared__ float wv[4];
  __shared__ int wi[4];
  __shared__ int am_s;
  float* feat = out + 80;
  int tid = threadIdx.x;
  const int NB = gridDim.x;

  for (int u = blockIdx.x; u < NUNITS; u += NB) {
    __syncthreads();
    stage_inlay(u, tid, arena, x, lin0, geo0, box0, db, ws1, out);
  }
  grid.sync();
  for (int u = blockIdx.x; u < NUNITS; u += NB) {
    __syncthreads();
    stage_gemm64(u, tid, arena, arena + 1088, lins, ws1, ws0);
  }
  grid.sync();
  for (int u = blockIdx.x; u < NUNITS; u += NB) {
    __syncthreads();
    stage_sampmax(u, tid, arena, arena + 4352, wv, wi, &am_s, ws0, geos, boxes, ws1);
  }
  grid.sync();
  for (int u = blockIdx.x; u < NUNITS; u += NB) {
    __syncthreads();
    stage_gemm32(u, tid, arena, arena + 576, lins + 16384, ws1, ws2);
  }
  grid.sync();
  for (int u = blockIdx.x; u < NUNITS; u += NB) {
    __syncthreads();
    stage_sample32<false>(u, tid, arena, wv, ws2, geos + 768, boxes + 768, ws0,
                          nullptr, nullptr);
  }
  grid.sync();
  for (int u = blockIdx.x; u < NUNITS; u += NB) {
    __syncthreads();
    stage_gemm32(u, tid, arena, arena + 576, lins + 32768, ws0, ws2);
  }
  grid.sync();
  for (int u = blockIdx.x; u < NUNITS; u += NB) {
    __syncthreads();
    stage_sample32<true>(u, tid, arena, wv, ws2, geos + 1536, boxes + 1536, feat,
                         dw, out);
  }
}

// ======================= fallback wrappers (verified round-3 pipeline) =============
__global__ __launch_bounds__(256) void k_inlay(
    const float* x, const float* lin0, const float* geo0, const float* box0,
    const float* db, float* ws1, float* head) {
  __shared__ __align__(16) float cp[67 * 68];
  stage_inlay(blockIdx.x, threadIdx.x, cp, x, lin0, geo0, box0, db, ws1, head);
}

__global__ __launch_bounds__(256) void k_gemm64(
    const float* lw, const float* xin, float* yout) {
  __shared__ __align__(16) float As[16 * 68];
  __shared__ __align__(16) float Bs[16 * 64];
  stage_gemm64(blockIdx.x, threadIdx.x, As, Bs, lw, xin, yout);
}

__global__ __launch_bounds__(256) void k_sampmax(
    const float* yin, const float* geo, const float* box, float* outp) {
  __shared__ __align__(16) float sp[64 * 68];
  __shared__ __align__(16) float pl[67 * 68];
  __shared__ float wv[4];
  __shared__ int wi[4];
  __shared__ int am_s;
  stage_sampmax(blockIdx.x, threadIdx.x, sp, pl, wv, wi, &am_s, yin, geo, box, outp);
}

__global__ __launch_bounds__(256) void k_gemm32(
    const float* lw, const float* xin, float* yout) {
  __shared__ __align__(16) float As[16 * 36];
  __shared__ __align__(16) float Bs[16 * 32];
  stage_gemm32(blockIdx.x, threadIdx.x, As, Bs, lw, xin, yout);
}

template <bool POOL>
__global__ __launch_bounds__(256) void k_sample32(
    const float* yin, const float* geo, const float* box, float* outp,
    const float* dw, float* head) {
  __shared__ float pl[35 * 36];
  __shared__ float wred[4];
  stage_sample32<POOL>(blockIdx.x, threadIdx.x, pl, wred, yin, geo, box, outp, dw, head);
}

extern "C" void kernel_launch(void* const* d_in, const int* in_sizes, int n_in,
                              void* d_out, int out_size, void* d_ws, size_t ws_size,
                              hipStream_t stream) {
  const float* x     = (const float*)d_in[0];   // [8,3,64,64]
  const float* geo0  = (const float*)d_in[1];   // [128,2,3]
  const float* lin0  = (const float*)d_in[2];   // [128,3]
  const float* box0  = (const float*)d_in[3];   // [128,2,3]
  const float* geos  = (const float*)d_in[4];   // [3,128,2,3]
  const float* lins  = (const float*)d_in[5];   // [3,128,128]
  const float* boxes = (const float*)d_in[6];   // [3,128,2,3]
  const float* dw    = (const float*)d_in[7];   // [10,128]
  const float* db    = (const float*)d_in[8];   // [10]

  float* out  = (float*)d_out;      // [8,10] then feat [8,128,32,32]
  float* feat = out + 80;
  float* ws   = (float*)d_ws;
  float* ws0  = ws;                 // 16 MB regions
  float* ws1  = ws + 4194304;
  float* ws2  = ws + 8388608;

  // Decide once: largest cooperative grid the runtime will accept (host-side
  // queries only -- capture-safe). <8 blocks => use fallback pipeline.
  static int coop_grid = -2;
  if (coop_grid == -2) {
    int occ = 0, cus = 0, dev = 0;
    if (hipGetDevice(&dev) == hipSuccess &&
        hipDeviceGetAttribute(&cus, hipDeviceAttributeMultiprocessorCount, dev) == hipSuccess &&
        hipOccupancyMaxActiveBlocksPerMultiprocessor(
            &occ, (const void*)meganet_kernel, 256, 0) == hipSuccess &&
        occ > 0 && cus > 0) {
      long cap = (long)occ * (long)cus;
      coop_grid = (int)(cap < NUNITS ? cap : NUNITS);
      if (coop_grid < 8) coop_grid = -1;
    } else {
      coop_grid = -1;
    }
  }

  bool done = false;
  if (coop_grid > 0) {
    void* args[] = {(void*)&x, (void*)&geo0, (void*)&lin0, (void*)&box0,
                    (void*)&geos, (void*)&lins, (void*)&boxes, (void*)&dw,
                    (void*)&db, (void*)&out, (void*)&ws0, (void*)&ws1, (void*)&ws2};
    hipError_t e = hipLaunchCooperativeKernel(
        reinterpret_cast<void*>(meganet_kernel), dim3(coop_grid), dim3(256),
        args, 0, stream);
    if (e == hipSuccess) {
      done = true;
    } else {
      coop_grid = -1;  // never try again
    }
  }

  if (!done) {
    k_inlay<<<dim3(NUNITS), 256, 0, stream>>>(x, lin0, geo0, box0, db, ws1, out);
    k_gemm64<<<dim3(NUNITS), 256, 0, stream>>>(lins, ws1, ws0);
    k_sampmax<<<dim3(NUNITS), 256, 0, stream>>>(ws0, geos, boxes, ws1);
    k_gemm32<<<dim3(NUNITS), 256, 0, stream>>>(lins + 16384, ws1, ws2);
    k_sample32<false><<<dim3(NUNITS), 256, 0, stream>>>(ws2, geos + 768, boxes + 768, ws0, nullptr, nullptr);
    k_gemm32<<<dim3(NUNITS), 256, 0, stream>>>(lins + 32768, ws0, ws2);
    k_sample32<true><<<dim3(NUNITS), 256, 0, stream>>>(ws2, geos + 1536, boxes + 1536, feat, dw, out);
  }
}

// Round 6
// 146.587 us; speedup vs baseline: 2.8506x; 2.8506x over previous
//
#include <hip/hip_runtime.h>

#define BB 8
#define CC 128

typedef _Float16 f16x4 __attribute__((ext_vector_type(4)));
typedef float f32x4 __attribute__((ext_vector_type(4)));

// Bilinear sample from a zero-border padded LDS plane.
// pl is [H+3][stride] with interior pixel (r,c) at pl[(r+1)*stride + (c+1)],
// border rows/cols are 0. Coords clamped to [-1, W]; out-of-range taps read 0.
__device__ __forceinline__ float sample_pad(const float* __restrict__ pl, int stride,
                                            float WF, float ix, float iy) {
  ix = fminf(fmaxf(ix, -1.0f), WF);
  iy = fminf(fmaxf(iy, -1.0f), WF);
  float x0f = floorf(ix), y0f = floorf(iy);
  float wx = ix - x0f, wy = iy - y0f;
  int xi = (int)x0f + 1, yi = (int)y0f + 1;
  const float* p0 = pl + yi * stride + xi;
  float v00 = p0[0], v01 = p0[1], v10 = p0[stride], v11 = p0[stride + 1];
  return (1.0f - wy) * ((1.0f - wx) * v00 + wx * v01) +
         wy * ((1.0f - wx) * v10 + wx * v11);
}

// Factorized box mask: validity of tap(i,j) = X_i * Y_j, so bilinear sum = mx*my.
__device__ __forceinline__ float box_mask(float bix, float biy, float WM1) {
  float bx0 = floorf(bix), by0 = floorf(biy);
  float bwx = bix - bx0, bwy = biy - by0;
  float mx = (((bx0 >= 0.0f) && (bx0 <= WM1)) ? (1.0f - bwx) : 0.0f) +
             (((bx0 >= -1.0f) && (bx0 <= WM1 - 1.0f)) ? bwx : 0.0f);
  float my = (((by0 >= 0.0f) && (by0 <= WM1)) ? (1.0f - bwy) : 0.0f) +
             (((by0 >= -1.0f) && (by0 <= WM1 - 1.0f)) ? bwy : 0.0f);
  return mx * my;
}

// ---------------- fused inLay: combine -> padded LDS + sample + box mask ----------
__global__ __launch_bounds__(256) void inlay_sample_kernel(
    const float* __restrict__ x, const float* __restrict__ lin,
    const float* __restrict__ geo, const float* __restrict__ box,
    const float* __restrict__ db, float* __restrict__ out,
    float* __restrict__ head) {
  const int H = 64, W = 64, HW = 4096;
  __shared__ float cp[67 * 68];
  int bc = blockIdx.x;
  int c = bc & (CC - 1);
  int b = bc >> 7;
  int tid = threadIdx.x;
  if (bc == 0 && tid < 80) head[tid] = db[tid % 10];  // bias init for atomic dense
  const float* xb = x + (size_t)b * 3 * HW;

  float w0 = lin[c * 3 + 0], w1 = lin[c * 3 + 1], w2 = lin[c * 3 + 2];

  if (tid < 68) {
    cp[tid] = 0.0f; cp[65 * 68 + tid] = 0.0f; cp[66 * 68 + tid] = 0.0f;
  } else if (tid < 132) {
    int r = tid - 67;
    cp[r * 68 + 0] = 0.0f; cp[r * 68 + 65] = 0.0f; cp[r * 68 + 66] = 0.0f;
  }

#pragma unroll
  for (int k = 0; k < 4; ++k) {
    int i4 = tid + k * 256;
    int base = i4 * 4;
    float4 f0 = *reinterpret_cast<const float4*>(&xb[base]);
    float4 f1 = *reinterpret_cast<const float4*>(&xb[HW + base]);
    float4 f2 = *reinterpret_cast<const float4*>(&xb[2 * HW + base]);
    int h = i4 >> 4, w = (i4 & 15) * 4;
    float* d = &cp[(h + 1) * 68 + w + 1];
    d[0] = w0 * f0.x + w1 * f1.x + w2 * f2.x;
    d[1] = w0 * f0.y + w1 * f1.y + w2 * f2.y;
    d[2] = w0 * f0.z + w1 * f1.z + w2 * f2.z;
    d[3] = w0 * f0.w + w1 * f1.w + w2 * f2.w;
  }
  __syncthreads();

  const float* g = geo + c * 6;
  const float* bx = box + c * 6;
  float g0 = g[0], g1 = g[1], g2 = g[2], g3 = g[3], g4 = g[4], g5 = g[5];
  float b0 = bx[0], b1 = bx[1], b2 = bx[2], b3 = bx[3], b4 = bx[4], b5 = bx[5];
  float* o = out + ((size_t)b * CC + c) * HW;

#pragma unroll
  for (int k = 0; k < 16; ++k) {
    int px = tid + k * 256;
    int h = px >> 6, w = px & 63;
    float xs = (2.0f * w + 1.0f) / W - 1.0f;
    float ys = (2.0f * h + 1.0f) / H - 1.0f;
    float ix = ((g0 * xs + g1 * ys + g2 + 1.0f) * W - 1.0f) * 0.5f;
    float iy = ((g3 * xs + g4 * ys + g5 + 1.0f) * H - 1.0f) * 0.5f;
    float samp = sample_pad(cp, 68, 64.0f, ix, iy);
    float bix = ((b0 * xs + b1 * ys + b2 + 1.0f) * W - 1.0f) * 0.5f;
    float biy = ((b3 * xs + b4 * ys + b5 + 1.0f) * H - 1.0f) * 0.5f;
    o[px] = samp * box_mask(bix, biy, 63.0f);
  }
}

// ---------------- layer-0 GEMM via f16 MFMA: 64x64 tile, single-stage LDS ----------
// A (lins) and B (x) staged once as k-pair-packed f16 words; one barrier; 4 waves,
// each computing a 16-row strip as 4 col-tiles x 8 mfma_f32_16x16x16f16.
// Layouts (gfx950-verified, m89 + AMD matrix calc):
//   A frag: lane l holds A[row=l&15][k=16s+4*(l>>4)+j]   (f16x4, one ds_read_b64)
//   B frag: lane l holds B[k=16s+4*(l>>4)+j][col=l&15]
//   D:      lane l holds D[row=4*(l>>4)+i][col=l&15]
__global__ __launch_bounds__(256) void gemm64_mfma_kernel(
    const float* __restrict__ lin, const float* __restrict__ x,
    float* __restrict__ y) {
  const int Ci = 128, HW = 4096;
  __shared__ unsigned int A_lds[64 * 66];  // [row][kp] kp = k/2, stride 66 (pad)
  __shared__ unsigned int B_lds[64 * 66];  // [col][kp]
  int b = blockIdx.z;
  int row0 = blockIdx.y * 64, col0 = blockIdx.x * 64;
  const float* xb = x + (size_t)b * Ci * HW;
  float* yb = y + (size_t)b * CC * HW;
  int tid = threadIdx.x;

  // stage A: thread t -> row = t>>2, k-chunk (t&3)*32 (16 packed words)
  {
    int row = tid >> 2, kc = (tid & 3) * 32;
    const float* ap = &lin[(row0 + row) * Ci + kc];
    unsigned int* dst = &A_lds[row * 66 + (kc >> 1)];
#pragma unroll
    for (int i = 0; i < 8; ++i) {
      float4 v = *reinterpret_cast<const float4*>(ap + i * 4);
      union { _Float16 h[2]; unsigned int u; } p0, p1;
      p0.h[0] = (_Float16)v.x; p0.h[1] = (_Float16)v.y;
      p1.h[0] = (_Float16)v.z; p1.h[1] = (_Float16)v.w;
      dst[i * 2] = p0.u; dst[i * 2 + 1] = p1.u;
    }
  }
  // stage B (transpose): thread t -> kp = t>>2 (rows k=2kp,2kp+1), cols (t&3)*16..+16
  {
    int kp = tid >> 2, cg = (tid & 3) * 16;
    const float* b0p = &xb[(size_t)(2 * kp) * HW + col0 + cg];
    const float* b1p = &xb[(size_t)(2 * kp + 1) * HW + col0 + cg];
#pragma unroll
    for (int q = 0; q < 4; ++q) {
      float4 v0 = *reinterpret_cast<const float4*>(b0p + q * 4);
      float4 v1 = *reinterpret_cast<const float4*>(b1p + q * 4);
      float e0[4] = {v0.x, v0.y, v0.z, v0.w};
      float e1[4] = {v1.x, v1.y, v1.z, v1.w};
#pragma unroll
      for (int c = 0; c < 4; ++c) {
        union { _Float16 h[2]; unsigned int u; } p;
        p.h[0] = (_Float16)e0[c]; p.h[1] = (_Float16)e1[c];
        B_lds[(cg + q * 4 + c) * 66 + kp] = p.u;
      }
    }
  }
  __syncthreads();

  int w = tid >> 6, l = tid & 63;
  int lr = l & 15, lq = l >> 4;
  f32x4 acc0 = {0.f, 0.f, 0.f, 0.f};
  f32x4 acc1 = acc0, acc2 = acc0, acc3 = acc0;
  const unsigned int* arow = &A_lds[(w * 16 + lr) * 66 + 2 * lq];
  const unsigned int* bcol = &B_lds[lr * 66 + 2 * lq];
#pragma unroll
  for (int s = 0; s < 8; ++s) {
    f16x4 af = *reinterpret_cast<const f16x4*>(arow + s * 8);
    f16x4 b0 = *reinterpret_cast<const f16x4*>(bcol + 0 * 16 * 66 + s * 8);
    f16x4 b1 = *reinterpret_cast<const f16x4*>(bcol + 1 * 16 * 66 + s * 8);
    f16x4 b2 = *reinterpret_cast<const f16x4*>(bcol + 2 * 16 * 66 + s * 8);
    f16x4 b3 = *reinterpret_cast<const f16x4*>(bcol + 3 * 16 * 66 + s * 8);
    acc0 = __builtin_amdgcn_mfma_f32_16x16x16f16(af, b0, acc0, 0, 0, 0);
    acc1 = __builtin_amdgcn_mfma_f32_16x16x16f16(af, b1, acc1, 0, 0, 0);
    acc2 = __builtin_amdgcn_mfma_f32_16x16x16f16(af, b2, acc2, 0, 0, 0);
    acc3 = __builtin_amdgcn_mfma_f32_16x16x16f16(af, b3, acc3, 0, 0, 0);
  }
  // write-out: rows w*16 + lq*4 + i, col ct*16 + lr
#pragma unroll
  for (int i = 0; i < 4; ++i) {
    float* yr = yb + (size_t)(row0 + w * 16 + lq * 4 + i) * HW + col0 + lr;
    yr[0]  = acc0[i];
    yr[16] = acc1[i];
    yr[32] = acc2[i];
    yr[48] = acc3[i];
  }
}

// ---------------- fused sample(64x64) + MaxPool2d_G -> 32x32, 256 threads ---------
__global__ __launch_bounds__(256) void sampmax_kernel(
    const float* __restrict__ y, const float* __restrict__ geo,
    const float* __restrict__ box, float* __restrict__ out) {
  __shared__ __align__(16) float sp[64 * 68];     // sampled plane
  __shared__ __align__(16) float arena[67 * 68];  // pl padded (ph0-1) then cb (ph2-3)
  __shared__ float wv[4];
  __shared__ int wi[4];
  __shared__ int am_s;
  float* pl = arena;
  float* cb = arena;

  int bc = blockIdx.x;
  int c = bc & (CC - 1);
  int tid = threadIdx.x;

  if (tid < 68) {
    pl[tid] = 0.0f; pl[65 * 68 + tid] = 0.0f; pl[66 * 68 + tid] = 0.0f;
  } else if (tid < 132) {
    int r = tid - 67;
    pl[r * 68 + 0] = 0.0f; pl[r * 68 + 65] = 0.0f; pl[r * 68 + 66] = 0.0f;
  }
  {
    const float* plane = y + (size_t)bc * 4096;
#pragma unroll
    for (int k = 0; k < 4; ++k) {
      int i4 = tid + k * 256;
      float4 f = *reinterpret_cast<const float4*>(&plane[i4 * 4]);
      int h = i4 >> 4, w = (i4 & 15) * 4;
      float* d = &pl[(h + 1) * 68 + w + 1];
      d[0] = f.x; d[1] = f.y; d[2] = f.z; d[3] = f.w;
    }
  }
  __syncthreads();

  {
    const float* g = geo + c * 6;
    const float* bx = box + c * 6;
    float g0 = g[0], g1 = g[1], g2 = g[2], g3 = g[3], g4 = g[4], g5 = g[5];
    float b0 = bx[0], b1 = bx[1], b2 = bx[2], b3 = bx[3], b4 = bx[4], b5 = bx[5];
#pragma unroll
    for (int k = 0; k < 16; ++k) {
      int px = tid + k * 256;
      int h = px >> 6, w = px & 63;
      float xs = (2.0f * w + 1.0f) / 64.0f - 1.0f;
      float ys = (2.0f * h + 1.0f) / 64.0f - 1.0f;
      float ix = ((g0 * xs + g1 * ys + g2 + 1.0f) * 64.0f - 1.0f) * 0.5f;
      float iy = ((g3 * xs + g4 * ys + g5 + 1.0f) * 64.0f - 1.0f) * 0.5f;
      float samp = sample_pad(pl, 68, 64.0f, ix, iy);
      float bix = ((b0 * xs + b1 * ys + b2 + 1.0f) * 64.0f - 1.0f) * 0.5f;
      float biy = ((b3 * xs + b4 * ys + b5 + 1.0f) * 64.0f - 1.0f) * 0.5f;
      sp[h * 68 + w] = samp * box_mask(bix, biy, 63.0f);
    }
  }
  __syncthreads();

  // Phase 2: vertical 32-row sliding box sums -> cb
  {
    int strip = tid >> 4, w4 = (tid & 15) * 4;
    int h0 = strip * 4;
    float4 a = make_float4(0.f, 0.f, 0.f, 0.f);
    float4 keep0 = a, keep1 = a, keep2 = a;
#pragma unroll
    for (int j = 0; j < 32; ++j) {
      int r = h0 + j - 16;
      bool valid = (r >= 0) && (r < 64);
      int rc = valid ? r : 0;
      float4 f = *reinterpret_cast<const float4*>(&sp[rc * 68 + w4]);
      f.x = valid ? f.x : 0.0f; f.y = valid ? f.y : 0.0f;
      f.z = valid ? f.z : 0.0f; f.w = valid ? f.w : 0.0f;
      if (j == 0) keep0 = f;
      if (j == 1) keep1 = f;
      if (j == 2) keep2 = f;
      a.x += f.x; a.y += f.y; a.z += f.z; a.w += f.w;
    }
    *reinterpret_cast<float4*>(&cb[(h0 + 0) * 68 + w4]) = a;
#pragma unroll
    for (int j = 32; j < 35; ++j) {
      int r = h0 + j - 16;
      bool valid = (r < 64);
      int rc = valid ? r : 0;
      float4 f = *reinterpret_cast<const float4*>(&sp[rc * 68 + w4]);
      f.x = valid ? f.x : 0.0f; f.y = valid ? f.y : 0.0f;
      f.z = valid ? f.z : 0.0f; f.w = valid ? f.w : 0.0f;
      float4 kp = (j == 32) ? keep0 : ((j == 33) ? keep1 : keep2);
      a.x += f.x - kp.x; a.y += f.y - kp.y; a.z += f.z - kp.z; a.w += f.w - kp.w;
      *reinterpret_cast<float4*>(&cb[(h0 + j - 31) * 68 + w4]) = a;
    }
  }
  __syncthreads();

  // Phase 3: horizontal 32-col sliding box sums + argmax
  float best = -3.402823466e+38f;
  int bidx = 0x7fffffff;
#pragma unroll
  for (int hh = 0; hh < 4; ++hh) {
    int h = (tid >> 4) + hh * 16;
    int w4 = (tid & 15) * 4;
    float s0 = 0.f, k0 = 0.f, k1 = 0.f, k2 = 0.f;
#pragma unroll
    for (int q = 0; q < 8; ++q) {
      int u0 = w4 - 16 + 4 * q;
      bool ok = (u0 >= 0) && (u0 <= 60);
      int uc = ok ? u0 : 0;
      float4 f = *reinterpret_cast<const float4*>(&cb[h * 68 + uc]);
      f.x = ok ? f.x : 0.0f; f.y = ok ? f.y : 0.0f;
      f.z = ok ? f.z : 0.0f; f.w = ok ? f.w : 0.0f;
      if (q == 0) { k0 = f.x; k1 = f.y; k2 = f.z; }
      s0 += f.x; s0 += f.y; s0 += f.z; s0 += f.w;
    }
    float ftx = 0.f, fty = 0.f, ftz = 0.f;
    {
      int u0 = w4 + 16;
      bool ok = (u0 <= 60);
      int uc = ok ? u0 : 0;
      float4 f = *reinterpret_cast<const float4*>(&cb[h * 68 + uc]);
      ftx = ok ? f.x : 0.0f; fty = ok ? f.y : 0.0f; ftz = ok ? f.z : 0.0f;
    }
    float s1 = s0 - k0 + ftx;
    float s2 = s1 - k1 + fty;
    float s3 = s2 - k2 + ftz;
    float sv[4] = {s0, s1, s2, s3};
#pragma unroll
    for (int d = 0; d < 4; ++d) {
      int i = (h << 6) + w4 + d;
      if (sv[d] > best) { best = sv[d]; bidx = i; }
    }
  }
#pragma unroll
  for (int off = 32; off > 0; off >>= 1) {
    float v2 = __shfl_down(best, off);
    int i2 = __shfl_down(bidx, off);
    if (v2 > best || (v2 == best && i2 < bidx)) { best = v2; bidx = i2; }
  }
  if ((tid & 63) == 0) { wv[tid >> 6] = best; wi[tid >> 6] = bidx; }
  __syncthreads();
  if (tid == 0) {
    float bv = wv[0]; int bi = wi[0];
#pragma unroll
    for (int k = 1; k < 4; ++k)
      if (wv[k] > bv || (wv[k] == bv && wi[k] < bi)) { bv = wv[k]; bi = wi[k]; }
    am_s = bi;
  }
  __syncthreads();

  int am = am_s;
  int r = am >> 6, cx = am & 63;
  float* o = out + (size_t)bc * 1024;
#pragma unroll
  for (int k = 0; k < 4; ++k) {
    int idx = tid + k * 256;
    int oi = idx >> 5, oj = idx & 31;
    int rr = r + oi - 16, cj = cx + oj - 16;
    bool v = (rr >= 0) && (rr < 64) && (cj >= 0) && (cj < 64);
    int rrc = v ? rr : 0, cjc = v ? cj : 0;
    o[idx] = v ? sp[rrc * 68 + cjc] : 0.0f;
  }
}

// ---------------- tiled 32x32-layer GEMM: 32x64 tiles, 2x4/thread ----------
__global__ __launch_bounds__(256) void gemm32_kernel(
    const float* __restrict__ lin, const float* __restrict__ x,
    float* __restrict__ y) {
  const int Ci = 128, HW = 1024;
  __shared__ __align__(16) float As[16][36];
  __shared__ __align__(16) float Bs[16][64];
  int b = blockIdx.z;
  const float* xb = x + (size_t)b * Ci * HW;
  float* yb = y + (size_t)b * CC * HW;
  int tid = threadIdx.x;
  int tx = tid & 15, ty = tid >> 4;
  int row0 = blockIdx.y * 32;
  int col0 = blockIdx.x * 64;
  int m = tid >> 2, kq = (tid & 3) * 4;
  int kk = tid >> 4, n4 = (tid & 15) * 4;
  float acc[2][4] = {};
  float4 ra = make_float4(0.f, 0.f, 0.f, 0.f);
  if (tid < 128) ra = *reinterpret_cast<const float4*>(&lin[(row0 + m) * Ci + kq]);
  float4 rb = *reinterpret_cast<const float4*>(&xb[(size_t)kk * HW + col0 + n4]);
  for (int k0 = 0; k0 < 128; k0 += 16) {
    __syncthreads();
    if (tid < 128) { As[kq + 0][m] = ra.x; As[kq + 1][m] = ra.y; As[kq + 2][m] = ra.z; As[kq + 3][m] = ra.w; }
    *reinterpret_cast<float4*>(&Bs[kk][n4]) = rb;
    __syncthreads();
    if (k0 + 16 < 128) {
      if (tid < 128) ra = *reinterpret_cast<const float4*>(&lin[(row0 + m) * Ci + k0 + 16 + kq]);
      rb = *reinterpret_cast<const float4*>(&xb[(size_t)(k0 + 16 + kk) * HW + col0 + n4]);
    }
#pragma unroll
    for (int kki = 0; kki < 16; ++kki) {
      float a0 = As[kki][ty * 2], a1 = As[kki][ty * 2 + 1];
      float4 b4 = *reinterpret_cast<const float4*>(&Bs[kki][tx * 4]);
      acc[0][0] += a0 * b4.x; acc[0][1] += a0 * b4.y; acc[0][2] += a0 * b4.z; acc[0][3] += a0 * b4.w;
      acc[1][0] += a1 * b4.x; acc[1][1] += a1 * b4.y; acc[1][2] += a1 * b4.z; acc[1][3] += a1 * b4.w;
    }
  }
#pragma unroll
  for (int i = 0; i < 2; i++) {
    float* yr = yb + (size_t)(row0 + ty * 2 + i) * HW + col0 + tx * 4;
    *reinterpret_cast<float4*>(yr) = make_float4(acc[i][0], acc[i][1], acc[i][2], acc[i][3]);
  }
}

// ---------------- 32x32 sample (+optional mean-pool + dense-head atomics) --------
template <bool POOL>
__global__ __launch_bounds__(256) void sample32_kernel(
    const float* __restrict__ y, const float* __restrict__ geo,
    const float* __restrict__ box, float* __restrict__ out,
    const float* __restrict__ dw, float* __restrict__ head) {
  const int W = 32, HW = 1024;
  __shared__ float pl[35 * 36];
  __shared__ float wred[4];
  int bc = blockIdx.x;
  int c = bc & (CC - 1);
  int b = bc >> 7;
  int tid = threadIdx.x;

  if (tid < 36) {
    pl[tid] = 0.0f; pl[33 * 36 + tid] = 0.0f; pl[34 * 36 + tid] = 0.0f;
  } else if (tid < 68) {
    int r = tid - 35;
    pl[r * 36 + 0] = 0.0f; pl[r * 36 + 33] = 0.0f; pl[r * 36 + 34] = 0.0f; pl[r * 36 + 35] = 0.0f;
  }
  {
    const float* plane = y + (size_t)bc * HW;
    float4 f = *reinterpret_cast<const float4*>(&plane[tid * 4]);
    int h = tid >> 3, w = (tid & 7) * 4;
    float* d = &pl[(h + 1) * 36 + w + 1];
    d[0] = f.x; d[1] = f.y; d[2] = f.z; d[3] = f.w;
  }
  __syncthreads();

  const float* g = geo + c * 6;
  const float* bxp = box + c * 6;
  float g0 = g[0], g1 = g[1], g2 = g[2], g3 = g[3], g4 = g[4], g5 = g[5];
  float b0 = bxp[0], b1 = bxp[1], b2 = bxp[2], b3 = bxp[3], b4 = bxp[4], b5 = bxp[5];
  float* o = out + (size_t)bc * HW;
  float psum = 0.f;
#pragma unroll
  for (int k = 0; k < 4; ++k) {
    int px = tid + k * 256;
    int h = px >> 5, w = px & 31;
    float xs = (2.0f * w + 1.0f) / W - 1.0f;
    float ys = (2.0f * h + 1.0f) / W - 1.0f;
    float ix = ((g0 * xs + g1 * ys + g2 + 1.0f) * W - 1.0f) * 0.5f;
    float iy = ((g3 * xs + g4 * ys + g5 + 1.0f) * W - 1.0f) * 0.5f;
    float samp = sample_pad(pl, 36, 32.0f, ix, iy);
    float bix = ((b0 * xs + b1 * ys + b2 + 1.0f) * W - 1.0f) * 0.5f;
    float biy = ((b3 * xs + b4 * ys + b5 + 1.0f) * W - 1.0f) * 0.5f;
    float res = samp * box_mask(bix, biy, 31.0f);
    o[px] = res;
    if (POOL) psum += res;
  }
  if (POOL) {
    int lane = tid & 63, wid = tid >> 6;  // 4 waves
    float r = psum;
#pragma unroll
    for (int off = 32; off > 0; off >>= 1) r += __shfl_down(r, off);
    if (lane == 0) wred[wid] = r;
    __syncthreads();
    if (tid < 10) {
      float t = (wred[0] + wred[1] + wred[2] + wred[3]) * (1.0f / 1024.0f);
      atomicAdd(&head[b * 10 + tid], t * dw[tid * 128 + c]);
    }
  }
}

extern "C" void kernel_launch(void* const* d_in, const int* in_sizes, int n_in,
                              void* d_out, int out_size, void* d_ws, size_t ws_size,
                              hipStream_t stream) {
  const float* x     = (const float*)d_in[0];   // [8,3,64,64]
  const float* geo0  = (const float*)d_in[1];   // [128,2,3]
  const float* lin0  = (const float*)d_in[2];   // [128,3]
  const float* box0  = (const float*)d_in[3];   // [128,2,3]
  const float* geos  = (const float*)d_in[4];   // [3,128,2,3]
  const float* lins  = (const float*)d_in[5];   // [3,128,128]
  const float* boxes = (const float*)d_in[6];   // [3,128,2,3]
  const float* dw    = (const float*)d_in[7];   // [10,128]
  const float* db    = (const float*)d_in[8];   // [10]

  float* out  = (float*)d_out;      // [8,10] then feat [8,128,32,32]
  float* feat = out + 80;
  float* ws   = (float*)d_ws;
  float* ws0  = ws;                 // 16 MB regions
  float* ws1  = ws + 4194304;
  float* ws2  = ws + 8388608;

  // inLay: fused combine(Ci=3) + sample -> ws1; also writes head bias
  inlay_sample_kernel<<<dim3(BB * CC), 256, 0, stream>>>(x, lin0, geo0, box0, db, ws1, out);
  // layer 0: f16-MFMA GEMM (64x64 tiles) -> fused sample+maxpool -> 32x32
  gemm64_mfma_kernel<<<dim3(64, 2, BB), 256, 0, stream>>>(lins, ws1, ws0);
  sampmax_kernel<<<dim3(BB * CC), 256, 0, stream>>>(ws0, geos, boxes, ws1);
  // layer 2: tiled GEMM then sample
  gemm32_kernel<<<dim3(16, 4, BB), 256, 0, stream>>>(lins + 16384, ws1, ws2);
  sample32_kernel<false><<<dim3(BB * CC), 256, 0, stream>>>(ws2, geos + 768, boxes + 768, ws0, nullptr, nullptr);
  // layer 3: tiled GEMM then sample + mean-pool + dense head
  gemm32_kernel<<<dim3(16, 4, BB), 256, 0, stream>>>(lins + 32768, ws0, ws2);
  sample32_kernel<true><<<dim3(BB * CC), 256, 0, stream>>>(ws2, geos + 1536, boxes + 1536, feat, dw, out);
}

// Round 7
// 140.461 us; speedup vs baseline: 2.9749x; 1.0436x over previous
//
#include <hip/hip_runtime.h>

#define BB 8
#define CC 128

typedef _Float16 f16x4 __attribute__((ext_vector_type(4)));
typedef float f32x4 __attribute__((ext_vector_type(4)));

// Bilinear sample from a zero-border padded LDS plane.
// pl is [H+3][stride] with interior pixel (r,c) at pl[(r+1)*stride + (c+1)],
// border rows/cols are 0. Coords clamped to [-1, W]; out-of-range taps read 0.
__device__ __forceinline__ float sample_pad(const float* __restrict__ pl, int stride,
                                            float WF, float ix, float iy) {
  ix = fminf(fmaxf(ix, -1.0f), WF);
  iy = fminf(fmaxf(iy, -1.0f), WF);
  float x0f = floorf(ix), y0f = floorf(iy);
  float wx = ix - x0f, wy = iy - y0f;
  int xi = (int)x0f + 1, yi = (int)y0f + 1;
  const float* p0 = pl + yi * stride + xi;
  float v00 = p0[0], v01 = p0[1], v10 = p0[stride], v11 = p0[stride + 1];
  return (1.0f - wy) * ((1.0f - wx) * v00 + wx * v01) +
         wy * ((1.0f - wx) * v10 + wx * v11);
}

// Factorized box mask: validity of tap(i,j) = X_i * Y_j, so bilinear sum = mx*my.
__device__ __forceinline__ float box_mask(float bix, float biy, float WM1) {
  float bx0 = floorf(bix), by0 = floorf(biy);
  float bwx = bix - bx0, bwy = biy - by0;
  float mx = (((bx0 >= 0.0f) && (bx0 <= WM1)) ? (1.0f - bwx) : 0.0f) +
             (((bx0 >= -1.0f) && (bx0 <= WM1 - 1.0f)) ? bwx : 0.0f);
  float my = (((by0 >= 0.0f) && (by0 <= WM1)) ? (1.0f - bwy) : 0.0f) +
             (((by0 >= -1.0f) && (by0 <= WM1 - 1.0f)) ? bwy : 0.0f);
  return mx * my;
}

// ---------------- fused inLay: combine -> padded LDS + sample + box mask ----------
__global__ __launch_bounds__(256) void inlay_sample_kernel(
    const float* __restrict__ x, const float* __restrict__ lin,
    const float* __restrict__ geo, const float* __restrict__ box,
    const float* __restrict__ db, float* __restrict__ out,
    float* __restrict__ head) {
  const int H = 64, W = 64, HW = 4096;
  __shared__ float cp[67 * 68];
  int bc = blockIdx.x;
  int c = bc & (CC - 1);
  int b = bc >> 7;
  int tid = threadIdx.x;
  if (bc == 0 && tid < 80) head[tid] = db[tid % 10];  // bias init for atomic dense
  const float* xb = x + (size_t)b * 3 * HW;

  float w0 = lin[c * 3 + 0], w1 = lin[c * 3 + 1], w2 = lin[c * 3 + 2];

  if (tid < 68) {
    cp[tid] = 0.0f; cp[65 * 68 + tid] = 0.0f; cp[66 * 68 + tid] = 0.0f;
  } else if (tid < 132) {
    int r = tid - 67;
    cp[r * 68 + 0] = 0.0f; cp[r * 68 + 65] = 0.0f; cp[r * 68 + 66] = 0.0f;
  }

#pragma unroll
  for (int k = 0; k < 4; ++k) {
    int i4 = tid + k * 256;
    int base = i4 * 4;
    float4 f0 = *reinterpret_cast<const float4*>(&xb[base]);
    float4 f1 = *reinterpret_cast<const float4*>(&xb[HW + base]);
    float4 f2 = *reinterpret_cast<const float4*>(&xb[2 * HW + base]);
    int h = i4 >> 4, w = (i4 & 15) * 4;
    float* d = &cp[(h + 1) * 68 + w + 1];
    d[0] = w0 * f0.x + w1 * f1.x + w2 * f2.x;
    d[1] = w0 * f0.y + w1 * f1.y + w2 * f2.y;
    d[2] = w0 * f0.z + w1 * f1.z + w2 * f2.z;
    d[3] = w0 * f0.w + w1 * f1.w + w2 * f2.w;
  }
  __syncthreads();

  const float* g = geo + c * 6;
  const float* bx = box + c * 6;
  float g0 = g[0], g1 = g[1], g2 = g[2], g3 = g[3], g4 = g[4], g5 = g[5];
  float b0 = bx[0], b1 = bx[1], b2 = bx[2], b3 = bx[3], b4 = bx[4], b5 = bx[5];
  float* o = out + ((size_t)b * CC + c) * HW;

#pragma unroll
  for (int k = 0; k < 16; ++k) {
    int px = tid + k * 256;
    int h = px >> 6, w = px & 63;
    float xs = (2.0f * w + 1.0f) / W - 1.0f;
    float ys = (2.0f * h + 1.0f) / H - 1.0f;
    float ix = ((g0 * xs + g1 * ys + g2 + 1.0f) * W - 1.0f) * 0.5f;
    float iy = ((g3 * xs + g4 * ys + g5 + 1.0f) * H - 1.0f) * 0.5f;
    float samp = sample_pad(cp, 68, 64.0f, ix, iy);
    float bix = ((b0 * xs + b1 * ys + b2 + 1.0f) * W - 1.0f) * 0.5f;
    float biy = ((b3 * xs + b4 * ys + b5 + 1.0f) * H - 1.0f) * 0.5f;
    o[px] = samp * box_mask(bix, biy, 63.0f);
  }
}

// ---------------- layer-0 GEMM via f16 MFMA: 64x64 tile, single-stage LDS ----------
// Layouts verified in round 6 (passed, absmax 256 << 1193):
//   A frag: lane l holds A[row=l&15][k=16s+4*(l>>4)+j]   (f16x4, one ds_read_b64)
//   B frag: lane l holds B[k=16s+4*(l>>4)+j][col=l&15]
//   D:      lane l holds D[row=4*(l>>4)+i][col=l&15]
__global__ __launch_bounds__(256) void gemm64_mfma_kernel(
    const float* __restrict__ lin, const float* __restrict__ x,
    float* __restrict__ y) {
  const int Ci = 128, HW = 4096;
  __shared__ unsigned int A_lds[64 * 66];  // [row][kp] kp = k/2, stride 66 (pad)
  __shared__ unsigned int B_lds[64 * 66];  // [col][kp]
  int b = blockIdx.z;
  int row0 = blockIdx.y * 64, col0 = blockIdx.x * 64;
  const float* xb = x + (size_t)b * Ci * HW;
  float* yb = y + (size_t)b * CC * HW;
  int tid = threadIdx.x;

  // stage A: thread t -> row = t>>2, k-chunk (t&3)*32 (16 packed words)
  {
    int row = tid >> 2, kc = (tid & 3) * 32;
    const float* ap = &lin[(row0 + row) * Ci + kc];
    unsigned int* dst = &A_lds[row * 66 + (kc >> 1)];
#pragma unroll
    for (int i = 0; i < 8; ++i) {
      float4 v = *reinterpret_cast<const float4*>(ap + i * 4);
      union { _Float16 h[2]; unsigned int u; } p0, p1;
      p0.h[0] = (_Float16)v.x; p0.h[1] = (_Float16)v.y;
      p1.h[0] = (_Float16)v.z; p1.h[1] = (_Float16)v.w;
      dst[i * 2] = p0.u; dst[i * 2 + 1] = p1.u;
    }
  }
  // stage B (transpose): thread t -> kp = t>>2 (rows k=2kp,2kp+1), cols (t&3)*16..+16
  {
    int kp = tid >> 2, cg = (tid & 3) * 16;
    const float* b0p = &xb[(size_t)(2 * kp) * HW + col0 + cg];
    const float* b1p = &xb[(size_t)(2 * kp + 1) * HW + col0 + cg];
#pragma unroll
    for (int q = 0; q < 4; ++q) {
      float4 v0 = *reinterpret_cast<const float4*>(b0p + q * 4);
      float4 v1 = *reinterpret_cast<const float4*>(b1p + q * 4);
      float e0[4] = {v0.x, v0.y, v0.z, v0.w};
      float e1[4] = {v1.x, v1.y, v1.z, v1.w};
#pragma unroll
      for (int c = 0; c < 4; ++c) {
        union { _Float16 h[2]; unsigned int u; } p;
        p.h[0] = (_Float16)e0[c]; p.h[1] = (_Float16)e1[c];
        B_lds[(cg + q * 4 + c) * 66 + kp] = p.u;
      }
    }
  }
  __syncthreads();

  int w = tid >> 6, l = tid & 63;
  int lr = l & 15, lq = l >> 4;
  f32x4 acc0 = {0.f, 0.f, 0.f, 0.f};
  f32x4 acc1 = acc0, acc2 = acc0, acc3 = acc0;
  const unsigned int* arow = &A_lds[(w * 16 + lr) * 66 + 2 * lq];
  const unsigned int* bcol = &B_lds[lr * 66 + 2 * lq];
#pragma unroll
  for (int s = 0; s < 8; ++s) {
    f16x4 af = *reinterpret_cast<const f16x4*>(arow + s * 8);
    f16x4 b0 = *reinterpret_cast<const f16x4*>(bcol + 0 * 16 * 66 + s * 8);
    f16x4 b1 = *reinterpret_cast<const f16x4*>(bcol + 1 * 16 * 66 + s * 8);
    f16x4 b2 = *reinterpret_cast<const f16x4*>(bcol + 2 * 16 * 66 + s * 8);
    f16x4 b3 = *reinterpret_cast<const f16x4*>(bcol + 3 * 16 * 66 + s * 8);
    acc0 = __builtin_amdgcn_mfma_f32_16x16x16f16(af, b0, acc0, 0, 0, 0);
    acc1 = __builtin_amdgcn_mfma_f32_16x16x16f16(af, b1, acc1, 0, 0, 0);
    acc2 = __builtin_amdgcn_mfma_f32_16x16x16f16(af, b2, acc2, 0, 0, 0);
    acc3 = __builtin_amdgcn_mfma_f32_16x16x16f16(af, b3, acc3, 0, 0, 0);
  }
#pragma unroll
  for (int i = 0; i < 4; ++i) {
    float* yr = yb + (size_t)(row0 + w * 16 + lq * 4 + i) * HW + col0 + lr;
    yr[0]  = acc0[i];
    yr[16] = acc1[i];
    yr[32] = acc2[i];
    yr[48] = acc3[i];
  }
}

// ---------------- 32x32-layer GEMM via f16 MFMA: M=32ch x N=64px, K=128 ----------
// Same fragment layouts/pack scheme as gemm64_mfma (verified). One barrier.
// Wave w: row strip (w&1)*16, col tiles (w>>1)*2 + {0,1}.
__global__ __launch_bounds__(256) void gemm32_mfma_kernel(
    const float* __restrict__ lin, const float* __restrict__ x,
    float* __restrict__ y) {
  const int Ci = 128, HW = 1024;
  __shared__ unsigned int A_lds[32 * 66];  // [row(ch)][kp]
  __shared__ unsigned int B_lds[64 * 66];  // [col(px)][kp]
  int b = blockIdx.z;
  int row0 = blockIdx.y * 32, col0 = blockIdx.x * 64;
  const float* xb = x + (size_t)b * Ci * HW;
  float* yb = y + (size_t)b * CC * HW;
  int tid = threadIdx.x;

  // stage A: thread t -> row = t>>3 (0..31), k-chunk (t&7)*16 (8 packed words)
  {
    int row = tid >> 3, kc = (tid & 7) * 16;
    const float* ap = &lin[(row0 + row) * Ci + kc];
    unsigned int* dst = &A_lds[row * 66 + (kc >> 1)];
#pragma unroll
    for (int i = 0; i < 4; ++i) {
      float4 v = *reinterpret_cast<const float4*>(ap + i * 4);
      union { _Float16 h[2]; unsigned int u; } p0, p1;
      p0.h[0] = (_Float16)v.x; p0.h[1] = (_Float16)v.y;
      p1.h[0] = (_Float16)v.z; p1.h[1] = (_Float16)v.w;
      dst[i * 2] = p0.u; dst[i * 2 + 1] = p1.u;
    }
  }
  // stage B (transpose): thread t -> kp = t>>2 (0..63), cols (t&3)*16..+16
  {
    int kp = tid >> 2, cg = (tid & 3) * 16;
    const float* b0p = &xb[(size_t)(2 * kp) * HW + col0 + cg];
    const float* b1p = &xb[(size_t)(2 * kp + 1) * HW + col0 + cg];
#pragma unroll
    for (int q = 0; q < 4; ++q) {
      float4 v0 = *reinterpret_cast<const float4*>(b0p + q * 4);
      float4 v1 = *reinterpret_cast<const float4*>(b1p + q * 4);
      float e0[4] = {v0.x, v0.y, v0.z, v0.w};
      float e1[4] = {v1.x, v1.y, v1.z, v1.w};
#pragma unroll
      for (int c = 0; c < 4; ++c) {
        union { _Float16 h[2]; unsigned int u; } p;
        p.h[0] = (_Float16)e0[c]; p.h[1] = (_Float16)e1[c];
        B_lds[(cg + q * 4 + c) * 66 + kp] = p.u;
      }
    }
  }
  __syncthreads();

  int w = tid >> 6, l = tid & 63;
  int lr = l & 15, lq = l >> 4;
  int rs = (w & 1) * 16;       // row strip within 32 channels
  int ct0 = (w >> 1) * 2;      // first of two 16-col tiles
  f32x4 acc0 = {0.f, 0.f, 0.f, 0.f};
  f32x4 acc1 = acc0;
  const unsigned int* arow = &A_lds[(rs + lr) * 66 + 2 * lq];
  const unsigned int* bc0 = &B_lds[(ct0 * 16 + lr) * 66 + 2 * lq];
  const unsigned int* bc1 = &B_lds[((ct0 + 1) * 16 + lr) * 66 + 2 * lq];
#pragma unroll
  for (int s = 0; s < 8; ++s) {
    f16x4 af = *reinterpret_cast<const f16x4*>(arow + s * 8);
    f16x4 b0 = *reinterpret_cast<const f16x4*>(bc0 + s * 8);
    f16x4 b1 = *reinterpret_cast<const f16x4*>(bc1 + s * 8);
    acc0 = __builtin_amdgcn_mfma_f32_16x16x16f16(af, b0, acc0, 0, 0, 0);
    acc1 = __builtin_amdgcn_mfma_f32_16x16x16f16(af, b1, acc1, 0, 0, 0);
  }
#pragma unroll
  for (int i = 0; i < 4; ++i) {
    float* yr = yb + (size_t)(row0 + rs + lq * 4 + i) * HW + col0 + ct0 * 16 + lr;
    yr[0]  = acc0[i];
    yr[16] = acc1[i];
  }
}

// ---------------- fused sample(64x64) + MaxPool2d_G -> 32x32, 256 threads ---------
__global__ __launch_bounds__(256) void sampmax_kernel(
    const float* __restrict__ y, const float* __restrict__ geo,
    const float* __restrict__ box, float* __restrict__ out) {
  __shared__ __align__(16) float sp[64 * 68];     // sampled plane
  __shared__ __align__(16) float arena[67 * 68];  // pl padded (ph0-1) then cb (ph2-3)
  __shared__ float wv[4];
  __shared__ int wi[4];
  __shared__ int am_s;
  float* pl = arena;
  float* cb = arena;

  int bc = blockIdx.x;
  int c = bc & (CC - 1);
  int tid = threadIdx.x;

  if (tid < 68) {
    pl[tid] = 0.0f; pl[65 * 68 + tid] = 0.0f; pl[66 * 68 + tid] = 0.0f;
  } else if (tid < 132) {
    int r = tid - 67;
    pl[r * 68 + 0] = 0.0f; pl[r * 68 + 65] = 0.0f; pl[r * 68 + 66] = 0.0f;
  }
  {
    const float* plane = y + (size_t)bc * 4096;
#pragma unroll
    for (int k = 0; k < 4; ++k) {
      int i4 = tid + k * 256;
      float4 f = *reinterpret_cast<const float4*>(&plane[i4 * 4]);
      int h = i4 >> 4, w = (i4 & 15) * 4;
      float* d = &pl[(h + 1) * 68 + w + 1];
      d[0] = f.x; d[1] = f.y; d[2] = f.z; d[3] = f.w;
    }
  }
  __syncthreads();

  {
    const float* g = geo + c * 6;
    const float* bx = box + c * 6;
    float g0 = g[0], g1 = g[1], g2 = g[2], g3 = g[3], g4 = g[4], g5 = g[5];
    float b0 = bx[0], b1 = bx[1], b2 = bx[2], b3 = bx[3], b4 = bx[4], b5 = bx[5];
#pragma unroll
    for (int k = 0; k < 16; ++k) {
      int px = tid + k * 256;
      int h = px >> 6, w = px & 63;
      float xs = (2.0f * w + 1.0f) / 64.0f - 1.0f;
      float ys = (2.0f * h + 1.0f) / 64.0f - 1.0f;
      float ix = ((g0 * xs + g1 * ys + g2 + 1.0f) * 64.0f - 1.0f) * 0.5f;
      float iy = ((g3 * xs + g4 * ys + g5 + 1.0f) * 64.0f - 1.0f) * 0.5f;
      float samp = sample_pad(pl, 68, 64.0f, ix, iy);
      float bix = ((b0 * xs + b1 * ys + b2 + 1.0f) * 64.0f - 1.0f) * 0.5f;
      float biy = ((b3 * xs + b4 * ys + b5 + 1.0f) * 64.0f - 1.0f) * 0.5f;
      sp[h * 68 + w] = samp * box_mask(bix, biy, 63.0f);
    }
  }
  __syncthreads();

  // Phase 2: vertical 32-row sliding box sums -> cb
  {
    int strip = tid >> 4, w4 = (tid & 15) * 4;
    int h0 = strip * 4;
    float4 a = make_float4(0.f, 0.f, 0.f, 0.f);
    float4 keep0 = a, keep1 = a, keep2 = a;
#pragma unroll
    for (int j = 0; j < 32; ++j) {
      int r = h0 + j - 16;
      bool valid = (r >= 0) && (r < 64);
      int rc = valid ? r : 0;
      float4 f = *reinterpret_cast<const float4*>(&sp[rc * 68 + w4]);
      f.x = valid ? f.x : 0.0f; f.y = valid ? f.y : 0.0f;
      f.z = valid ? f.z : 0.0f; f.w = valid ? f.w : 0.0f;
      if (j == 0) keep0 = f;
      if (j == 1) keep1 = f;
      if (j == 2) keep2 = f;
      a.x += f.x; a.y += f.y; a.z += f.z; a.w += f.w;
    }
    *reinterpret_cast<float4*>(&cb[(h0 + 0) * 68 + w4]) = a;
#pragma unroll
    for (int j = 32; j < 35; ++j) {
      int r = h0 + j - 16;
      bool valid = (r < 64);
      int rc = valid ? r : 0;
      float4 f = *reinterpret_cast<const float4*>(&sp[rc * 68 + w4]);
      f.x = valid ? f.x : 0.0f; f.y = valid ? f.y : 0.0f;
      f.z = valid ? f.z : 0.0f; f.w = valid ? f.w : 0.0f;
      float4 kp = (j == 32) ? keep0 : ((j == 33) ? keep1 : keep2);
      a.x += f.x - kp.x; a.y += f.y - kp.y; a.z += f.z - kp.z; a.w += f.w - kp.w;
      *reinterpret_cast<float4*>(&cb[(h0 + j - 31) * 68 + w4]) = a;
    }
  }
  __syncthreads();

  // Phase 3: horizontal 32-col sliding box sums + argmax
  float best = -3.402823466e+38f;
  int bidx = 0x7fffffff;
#pragma unroll
  for (int hh = 0; hh < 4; ++hh) {
    int h = (tid >> 4) + hh * 16;
    int w4 = (tid & 15) * 4;
    float s0 = 0.f, k0 = 0.f, k1 = 0.f, k2 = 0.f;
#pragma unroll
    for (int q = 0; q < 8; ++q) {
      int u0 = w4 - 16 + 4 * q;
      bool ok = (u0 >= 0) && (u0 <= 60);
      int uc = ok ? u0 : 0;
      float4 f = *reinterpret_cast<const float4*>(&cb[h * 68 + uc]);
      f.x = ok ? f.x : 0.0f; f.y = ok ? f.y : 0.0f;
      f.z = ok ? f.z : 0.0f; f.w = ok ? f.w : 0.0f;
      if (q == 0) { k0 = f.x; k1 = f.y; k2 = f.z; }
      s0 += f.x; s0 += f.y; s0 += f.z; s0 += f.w;
    }
    float ftx = 0.f, fty = 0.f, ftz = 0.f;
    {
      int u0 = w4 + 16;
      bool ok = (u0 <= 60);
      int uc = ok ? u0 : 0;
      float4 f = *reinterpret_cast<const float4*>(&cb[h * 68 + uc]);
      ftx = ok ? f.x : 0.0f; fty = ok ? f.y : 0.0f; ftz = ok ? f.z : 0.0f;
    }
    float s1 = s0 - k0 + ftx;
    float s2 = s1 - k1 + fty;
    float s3 = s2 - k2 + ftz;
    float sv[4] = {s0, s1, s2, s3};
#pragma unroll
    for (int d = 0; d < 4; ++d) {
      int i = (h << 6) + w4 + d;
      if (sv[d] > best) { best = sv[d]; bidx = i; }
    }
  }
#pragma unroll
  for (int off = 32; off > 0; off >>= 1) {
    float v2 = __shfl_down(best, off);
    int i2 = __shfl_down(bidx, off);
    if (v2 > best || (v2 == best && i2 < bidx)) { best = v2; bidx = i2; }
  }
  if ((tid & 63) == 0) { wv[tid >> 6] = best; wi[tid >> 6] = bidx; }
  __syncthreads();
  if (tid == 0) {
    float bv = wv[0]; int bi = wi[0];
#pragma unroll
    for (int k = 1; k < 4; ++k)
      if (wv[k] > bv || (wv[k] == bv && wi[k] < bi)) { bv = wv[k]; bi = wi[k]; }
    am_s = bi;
  }
  __syncthreads();

  int am = am_s;
  int r = am >> 6, cx = am & 63;
  float* o = out + (size_t)bc * 1024;
#pragma unroll
  for (int k = 0; k < 4; ++k) {
    int idx = tid + k * 256;
    int oi = idx >> 5, oj = idx & 31;
    int rr = r + oi - 16, cj = cx + oj - 16;
    bool v = (rr >= 0) && (rr < 64) && (cj >= 0) && (cj < 64);
    int rrc = v ? rr : 0, cjc = v ? cj : 0;
    o[idx] = v ? sp[rrc * 68 + cjc] : 0.0f;
  }
}

// ---------------- 32x32 sample (+optional mean-pool + dense-head atomics) --------
template <bool POOL>
__global__ __launch_bounds__(256) void sample32_kernel(
    const float* __restrict__ y, const float* __restrict__ geo,
    const float* __restrict__ box, float* __restrict__ out,
    const float* __restrict__ dw, float* __restrict__ head) {
  const int W = 32, HW = 1024;
  __shared__ float pl[35 * 36];
  __shared__ float wred[4];
  int bc = blockIdx.x;
  int c = bc & (CC - 1);
  int b = bc >> 7;
  int tid = threadIdx.x;

  if (tid < 36) {
    pl[tid] = 0.0f; pl[33 * 36 + tid] = 0.0f; pl[34 * 36 + tid] = 0.0f;
  } else if (tid < 68) {
    int r = tid - 35;
    pl[r * 36 + 0] = 0.0f; pl[r * 36 + 33] = 0.0f; pl[r * 36 + 34] = 0.0f; pl[r * 36 + 35] = 0.0f;
  }
  {
    const float* plane = y + (size_t)bc * HW;
    float4 f = *reinterpret_cast<const float4*>(&plane[tid * 4]);
    int h = tid >> 3, w = (tid & 7) * 4;
    float* d = &pl[(h + 1) * 36 + w + 1];
    d[0] = f.x; d[1] = f.y; d[2] = f.z; d[3] = f.w;
  }
  __syncthreads();

  const float* g = geo + c * 6;
  const float* bxp = box + c * 6;
  float g0 = g[0], g1 = g[1], g2 = g[2], g3 = g[3], g4 = g[4], g5 = g[5];
  float b0 = bxp[0], b1 = bxp[1], b2 = bxp[2], b3 = bxp[3], b4 = bxp[4], b5 = bxp[5];
  float* o = out + (size_t)bc * HW;
  float psum = 0.f;
#pragma unroll
  for (int k = 0; k < 4; ++k) {
    int px = tid + k * 256;
    int h = px >> 5, w = px & 31;
    float xs = (2.0f * w + 1.0f) / W - 1.0f;
    float ys = (2.0f * h + 1.0f) / W - 1.0f;
    float ix = ((g0 * xs + g1 * ys + g2 + 1.0f) * W - 1.0f) * 0.5f;
    float iy = ((g3 * xs + g4 * ys + g5 + 1.0f) * W - 1.0f) * 0.5f;
    float samp = sample_pad(pl, 36, 32.0f, ix, iy);
    float bix = ((b0 * xs + b1 * ys + b2 + 1.0f) * W - 1.0f) * 0.5f;
    float biy = ((b3 * xs + b4 * ys + b5 + 1.0f) * W - 1.0f) * 0.5f;
    float res = samp * box_mask(bix, biy, 31.0f);
    o[px] = res;
    if (POOL) psum += res;
  }
  if (POOL) {
    int lane = tid & 63, wid = tid >> 6;  // 4 waves
    float r = psum;
#pragma unroll
    for (int off = 32; off > 0; off >>= 1) r += __shfl_down(r, off);
    if (lane == 0) wred[wid] = r;
    __syncthreads();
    if (tid < 10) {
      float t = (wred[0] + wred[1] + wred[2] + wred[3]) * (1.0f / 1024.0f);
      atomicAdd(&head[b * 10 + tid], t * dw[tid * 128 + c]);
    }
  }
}

extern "C" void kernel_launch(void* const* d_in, const int* in_sizes, int n_in,
                              void* d_out, int out_size, void* d_ws, size_t ws_size,
                              hipStream_t stream) {
  const float* x     = (const float*)d_in[0];   // [8,3,64,64]
  const float* geo0  = (const float*)d_in[1];   // [128,2,3]
  const float* lin0  = (const float*)d_in[2];   // [128,3]
  const float* box0  = (const float*)d_in[3];   // [128,2,3]
  const float* geos  = (const float*)d_in[4];   // [3,128,2,3]
  const float* lins  = (const float*)d_in[5];   // [3,128,128]
  const float* boxes = (const float*)d_in[6];   // [3,128,2,3]
  const float* dw    = (const float*)d_in[7];   // [10,128]
  const float* db    = (const float*)d_in[8];   // [10]

  float* out  = (float*)d_out;      // [8,10] then feat [8,128,32,32]
  float* feat = out + 80;
  float* ws   = (float*)d_ws;
  float* ws0  = ws;                 // 16 MB regions
  float* ws1  = ws + 4194304;
  float* ws2  = ws + 8388608;

  // inLay: fused combine(Ci=3) + sample -> ws1; also writes head bias
  inlay_sample_kernel<<<dim3(BB * CC), 256, 0, stream>>>(x, lin0, geo0, box0, db, ws1, out);
  // layer 0: f16-MFMA GEMM (64x64 tiles) -> fused sample+maxpool -> 32x32
  gemm64_mfma_kernel<<<dim3(64, 2, BB), 256, 0, stream>>>(lins, ws1, ws0);
  sampmax_kernel<<<dim3(BB * CC), 256, 0, stream>>>(ws0, geos, boxes, ws1);
  // layer 2: f16-MFMA GEMM then sample
  gemm32_mfma_kernel<<<dim3(16, 4, BB), 256, 0, stream>>>(lins + 16384, ws1, ws2);
  sample32_kernel<false><<<dim3(BB * CC), 256, 0, stream>>>(ws2, geos + 768, boxes + 768, ws0, nullptr, nullptr);
  // layer 3: f16-MFMA GEMM then sample + mean-pool + dense head
  gemm32_mfma_kernel<<<dim3(16, 4, BB), 256, 0, stream>>>(lins + 32768, ws0, ws2);
  sample32_kernel<true><<<dim3(BB * CC), 256, 0, stream>>>(ws2, geos + 1536, boxes + 1536, feat, dw, out);
}